// Round 4
// baseline (537.379 us; speedup 1.0000x reference)
//
#include <hip/hip_runtime.h>
#include <stdint.h>
#include <math.h>

#define D_IN   1024
#define NQKV   3072
#define NHEADS 16
#define DH     64
#define BATCH  4
#define SEQ    2048
#define MTOT   (BATCH*SEQ)   // 8192

typedef __bf16    bf16x8 __attribute__((ext_vector_type(8)));
typedef _Float16  f16x8  __attribute__((ext_vector_type(8)));
typedef float     f32x4  __attribute__((ext_vector_type(4)));

typedef __attribute__((address_space(3))) unsigned short       lds_us;
typedef __attribute__((address_space(1))) const unsigned short glb_us;

__device__ __forceinline__ unsigned short f2bf(float f) {
    union { float f; uint32_t u; } c; c.f = f;
    uint32_t u = c.u;
    uint32_t r = u + 0x7fffu + ((u >> 16) & 1u);  // RNE
    return (unsigned short)(r >> 16);
}
__device__ __forceinline__ float bf2f(unsigned short b) {
    union { uint32_t u; float f; } c; c.u = ((uint32_t)b) << 16;
    return c.f;
}
__device__ __forceinline__ uint32_t pkh(float a, float b) {
    auto h = __builtin_amdgcn_cvt_pkrtz(a, b);   // __fp16 ext_vector(2)
    uint32_t u;
    __builtin_memcpy(&u, &h, 4);
    return u;
}

// ---------------- stage 0a: x fp32 -> bf16 ----------------
__global__ void k_convert_x(const float* __restrict__ x, unsigned short* __restrict__ xb) {
    int i = blockIdx.x * 256 + threadIdx.x;
    float4 v = ((const float4*)x)[i];
    ushort4 o;
    o.x = f2bf(v.x); o.y = f2bf(v.y); o.z = f2bf(v.z); o.w = f2bf(v.w);
    ((ushort4*)xb)[i] = o;
}

// ---------------- stage 0b: W fp32 [K][N] -> Wt bf16 [N][K] ----------------
__global__ void k_convert_wt(const float* __restrict__ W, unsigned short* __restrict__ Wt) {
    __shared__ float tile[32][33];
    int tx = threadIdx.x, ty = threadIdx.y;
    int n0 = blockIdx.x * 32, k0 = blockIdx.y * 32;
    #pragma unroll
    for (int i = 0; i < 4; ++i) {
        int k = k0 + ty + i*8;
        tile[ty + i*8][tx] = W[(size_t)k * NQKV + n0 + tx];
    }
    __syncthreads();
    #pragma unroll
    for (int i = 0; i < 4; ++i) {
        int n = n0 + ty + i*8;
        Wt[(size_t)n * D_IN + k0 + tx] = f2bf(tile[tx][ty + i*8]);
    }
}

// ---------------- stage 1: QKV = x @ W + b, m97-style global_load_lds GEMM ----------------
// 128x128 tile, BK=32, unpadded LDS [128][32] (2-way bank alias = free), DMA staging.
// Q columns (col%192 < 64) pre-scaled by 0.125*log2e so k_attn's exp2 needs no mul.
__global__ __launch_bounds__(256) void k_gemm_qkv(
    const unsigned short* __restrict__ A,   // [8192][1024] bf16
    const unsigned short* __restrict__ Bt,  // [3072][1024] bf16
    const float* __restrict__ bias,         // [3072]
    unsigned short* __restrict__ C)         // [8192][3072] bf16
{
    __shared__ __align__(16) unsigned short As[128*32];
    __shared__ __align__(16) unsigned short Bs[128*32];
    const int t = threadIdx.x;
    const int wave = t >> 6, lane = t & 63, quad = lane >> 4, l15 = lane & 15;
    const int wm = wave >> 1, wn = wave & 1;
    const int m0 = blockIdx.y * 128, n0 = blockIdx.x * 128;
    const int crow = lane >> 2;          // row within 16-row chunk
    const int ccol = (lane & 3) << 3;    // short col within row

    f32x4 acc[4][4] = {};
    lds_us* As3 = (lds_us*)As;
    lds_us* Bs3 = (lds_us*)Bs;

    for (int k0 = 0; k0 < D_IN; k0 += 32) {
        // stage A,B tiles: each wave DMAs 2 chunks of 16 rows each (1024 B per instr)
        #pragma unroll
        for (int j = 0; j < 2; ++j) {
            int chunk = wave*2 + j;
            const unsigned short* ga = A  + (size_t)(m0 + chunk*16 + crow)*D_IN + k0 + ccol;
            const unsigned short* gb = Bt + (size_t)(n0 + chunk*16 + crow)*D_IN + k0 + ccol;
            __builtin_amdgcn_global_load_lds((glb_us*)ga, As3 + chunk*512, 16, 0, 0);
            __builtin_amdgcn_global_load_lds((glb_us*)gb, Bs3 + chunk*512, 16, 0, 0);
        }
        __syncthreads();   // drains vmcnt -> staging visible
        bf16x8 a[4], b[4];
        #pragma unroll
        for (int tm = 0; tm < 4; ++tm)
            a[tm] = *(const bf16x8*)(&As[(wm*64 + tm*16 + l15)*32 + quad*8]);
        #pragma unroll
        for (int tn = 0; tn < 4; ++tn)
            b[tn] = *(const bf16x8*)(&Bs[(wn*64 + tn*16 + l15)*32 + quad*8]);
        #pragma unroll
        for (int tm = 0; tm < 4; ++tm)
            #pragma unroll
            for (int tn = 0; tn < 4; ++tn)
                acc[tm][tn] = __builtin_amdgcn_mfma_f32_16x16x32_bf16(a[tm], b[tn], acc[tm][tn], 0, 0, 0);
        __syncthreads();   // protect LDS before next iteration's DMA overwrite
    }
    const float qs = 0.125f * 1.44269504089f;
    #pragma unroll
    for (int tn = 0; tn < 4; ++tn) {
        int col = n0 + wn*64 + tn*16 + l15;
        float bv = bias[col];
        float s = ((col % 192) < 64) ? qs : 1.0f;   // pre-scale Q columns
        #pragma unroll
        for (int tm = 0; tm < 4; ++tm) {
            #pragma unroll
            for (int r = 0; r < 4; ++r) {
                int row = m0 + wm*64 + tm*16 + quad*4 + r;
                C[(size_t)row*NQKV + col] = f2bf((acc[tm][tn][r] + bv) * s);
            }
        }
    }
}

// ---------------- stage 1b: V (bf16, strided in qkv) -> Vt f16 [bh][d][s] ----------------
// grid (bh, s-tile): all of one bh's V^T written on ONE XCD's L2 (matches k_attn's mapping).
#define TP 66
__global__ __launch_bounds__(256) void k_transpose_v(
    const unsigned short* __restrict__ qkv,
    unsigned short* __restrict__ vtg)       // f16 bits
{
    __shared__ unsigned short T[64*TP];     // [s][d] as f16
    const int t = threadIdx.x;
    const int bh = blockIdx.x, b = bh >> 4, h = bh & 15;
    const int s0 = blockIdx.y * 64;
    const unsigned short* src = qkv + (size_t)(b*SEQ + s0)*NQKV + h*(3*DH) + 2*DH;
    #pragma unroll
    for (int i = 0; i < 2; ++i) {
        int idx = t + i*256;
        int s = idx >> 3, c = (idx & 7) << 3;
        uint4 v = *(const uint4*)(src + (size_t)s*NQKV + c);   // 16 B = 8 bf16
        unsigned short* dst = &T[s*TP + c];
        const unsigned short* pv = (const unsigned short*)&v;
        #pragma unroll
        for (int j = 0; j < 8; ++j) {
            _Float16 hv = (_Float16)bf2f(pv[j]);
            dst[j] = *(unsigned short*)&hv;
        }
    }
    __syncthreads();
    unsigned short* out = vtg + (size_t)bh * DH * SEQ + s0;
    #pragma unroll
    for (int i = 0; i < 16; ++i) {
        int idx = t + i*256;
        int d = idx >> 6, s = idx & 63;
        out[(size_t)d * SEQ + s] = T[s*TP + d];
    }
}

// ---------------- stage 2: transposed flash attention, software-pipelined P ----------------
// R4: PV lags QK by one iteration (T15-style 1-deep pipeline).
// R3 post-mortem: occupancy 30% but dur only -4%; per-wave critical path was
// QK->exp->pkh->ds_write->lgkm drain->ds_read->PV, all serial. Now:
//   top of iter: issue pb ds_reads from Pl[prev] (data written a FULL iter ago;
//   read latency hides under the entire QK+exp phase). PV(it-1) is then pure
//   register MFMA with zero LDS waits. Pl double-buffered (2x20KB); Q tile (9KB)
//   stays in the PO union tail (aliasing pins Q reads in-loop, no LICM blowup).
// LDS 51.2KB -> 3 blocks/CU = exactly the 3-waves/SIMD register limit: free.
// pb[4] now persistent (+16 VGPR): combined ~160, still 3 waves/SIMD, no cap.
#define PPAD 40   // P^T row pitch (shorts): pb b128 reads conflict-free, writes 2-way (free)
#define OPAD 72   // O^T stash row pitch (shorts)
#define QPITCH 72 // Q tile row pitch (shorts)
#define PLSZ (4*64*PPAD)   // one Pl buffer, in shorts (10240)
__global__ __launch_bounds__(256, 2) void k_attn(
    const unsigned short* __restrict__ qkv, // bf16 (Q pre-scaled by 0.125*log2e)
    const unsigned short* __restrict__ vtg, // f16 V^T [bh][d][s]
    float* __restrict__ out)
{
    // PO layout (shorts): [0,10240) PlA | [10240,20480) PlB | [20480,25088) Q
    // epilogue Os (18432 shorts) unions over PlA+PlB (all dead by then)
    __shared__ __align__(16) unsigned short PO[2*PLSZ + 64*QPITCH];
    __shared__ float Lp[4*64];

    const int t = threadIdx.x;
    const int wave = t >> 6, lane = t & 63, quad = lane >> 4, l15 = lane & 15;
    const int bh = blockIdx.x, b = bh >> 4, h = bh & 15;
    const int m0 = blockIdx.y * 64;
    const unsigned short* base  = qkv + (size_t)(b*SEQ)*NQKV + h*(3*DH);
    const unsigned short* kbase = base + DH;
    const unsigned short* vbase = vtg + (size_t)bh * DH * SEQ;

    unsigned short* Qs = &PO[2*PLSZ];

    // cooperative Q stage: 64 rows x 64 cols bf16 -> LDS pitch QPITCH
    #pragma unroll
    for (int i = 0; i < 2; ++i) {
        int idx = t + i*256;
        int r = idx >> 3, cg = idx & 7;
        uint4 v = *(const uint4*)(base + (size_t)(m0 + r)*NQKV + cg*8);
        *(uint4*)(&Qs[r*QPITCH + cg*8]) = v;
    }

    f32x4 o[4][4] = {};            // O^T tiles [td][tq]: row=d, col=q
    float lp[4] = {0.f, 0.f, 0.f, 0.f};
    unsigned short* pl0 = &PO[wave*64*PPAD];
    unsigned short* pl1 = &PO[PLSZ + wave*64*PPAD];

    // single-buffered K/V fragments (direct global loads, L2-resident on this XCD)
    bf16x8 kf[2][2];   // [tk][kc]
    f16x8  vf[4];      // [td]  — holds the V tile for the PENDING (lagged) PV
    {
        int key0 = wave*32;
        #pragma unroll
        for (int tk = 0; tk < 2; ++tk) {
            const unsigned short* kr = kbase + (size_t)(key0 + tk*16 + l15)*NQKV;
            kf[tk][0] = *(const bf16x8*)(kr + quad*8);
            kf[tk][1] = *(const bf16x8*)(kr + 32 + quad*8);
        }
        #pragma unroll
        for (int td = 0; td < 4; ++td)
            vf[td] = *(const f16x8*)(vbase + (size_t)(td*16 + l15)*SEQ + key0 + quad*8);
    }
    __syncthreads();   // Q staged before first QK read

    // QK phase: S^T = K·Q^T for 32 keys, exp2, pack f16, store to Pl buffer.
    // C'[key][q]: row=key_local=tk*16+quad*4+r, col=q=tq*16+l15
#define QK_PHASE(PW)                                                              \
    _Pragma("unroll")                                                             \
    for (int tq = 0; tq < 4; ++tq) {                                              \
        bf16x8 q0 = *(const bf16x8*)(&Qs[(tq*16 + l15)*QPITCH + quad*8]);         \
        bf16x8 q1 = *(const bf16x8*)(&Qs[(tq*16 + l15)*QPITCH + 32 + quad*8]);    \
        _Pragma("unroll")                                                         \
        for (int tk = 0; tk < 2; ++tk) {                                          \
            f32x4 a = {};                                                         \
            __builtin_amdgcn_s_setprio(1);                                        \
            a = __builtin_amdgcn_mfma_f32_16x16x32_bf16(kf[tk][0], q0, a, 0, 0, 0); \
            a = __builtin_amdgcn_mfma_f32_16x16x32_bf16(kf[tk][1], q1, a, 0, 0, 0); \
            __builtin_amdgcn_s_setprio(0);                                        \
            float p0 = exp2f(a[0]), p1 = exp2f(a[1]);                             \
            float p2 = exp2f(a[2]), p3 = exp2f(a[3]);                             \
            lp[tq] += (p0 + p1) + (p2 + p3);                                      \
            uint2 u; u.x = pkh(p0, p1); u.y = pkh(p2, p3);                        \
            *(uint2*)(&(PW)[(tq*16 + l15)*PPAD + tk*16 + quad*4]) = u;            \
        }                                                                         \
    }

    // prologue: QK(0) -> PlA; prefetch kf <- tile 1
    QK_PHASE(pl0)
    {
        int key0 = 1*128 + wave*32;
        #pragma unroll
        for (int tk = 0; tk < 2; ++tk) {
            const unsigned short* kr = kbase + (size_t)(key0 + tk*16 + l15)*NQKV;
            kf[tk][0] = *(const bf16x8*)(kr + quad*8);
            kf[tk][1] = *(const bf16x8*)(kr + 32 + quad*8);
        }
    }

    f16x8 pb[4];
    #pragma unroll 2
    for (int it = 1; it < 16; ++it) {
        unsigned short* cur  = (it & 1) ? pl1 : pl0;
        unsigned short* prev = (it & 1) ? pl0 : pl1;
        // issue pb reads for PV(it-1) FIRST — latency hides under QK(it)
        #pragma unroll
        for (int tq = 0; tq < 4; ++tq)
            pb[tq] = *(const f16x8*)(&prev[(tq*16 + l15)*PPAD + quad*8]);
        // QK(it) -> Pl[cur]
        QK_PHASE(cur)
        // kf consumed -> reload with tile it+1 (PV below hides the latency)
        if (it < 15) {
            int key0 = (it+1)*128 + wave*32;
            #pragma unroll
            for (int tk = 0; tk < 2; ++tk) {
                const unsigned short* kr = kbase + (size_t)(key0 + tk*16 + l15)*NQKV;
                kf[tk][0] = *(const bf16x8*)(kr + quad*8);
                kf[tk][1] = *(const bf16x8*)(kr + 32 + quad*8);
            }
        }
        // PV(it-1): O^T += V^T(it-1) · P^T(it-1) — pure register MFMA
        __builtin_amdgcn_s_setprio(1);
        #pragma unroll
        for (int tq = 0; tq < 4; ++tq)
            #pragma unroll
            for (int td = 0; td < 4; ++td)
                o[td][tq] = __builtin_amdgcn_mfma_f32_16x16x32_f16(vf[td], pb[tq], o[td][tq], 0, 0, 0);
        __builtin_amdgcn_s_setprio(0);
        // vf consumed -> reload with tile it (next iter's lagged PV); QK(it+1) hides it
        {
            int key0 = it*128 + wave*32;
            #pragma unroll
            for (int td = 0; td < 4; ++td)
                vf[td] = *(const f16x8*)(vbase + (size_t)(td*16 + l15)*SEQ + key0 + quad*8);
        }
    }
    // epilogue PV(15): Pl[15&1]=pl1, vf holds tile 15
    {
        #pragma unroll
        for (int tq = 0; tq < 4; ++tq)
            pb[tq] = *(const f16x8*)(&pl1[(tq*16 + l15)*PPAD + quad*8]);
        __builtin_amdgcn_s_setprio(1);
        #pragma unroll
        for (int tq = 0; tq < 4; ++tq)
            #pragma unroll
            for (int td = 0; td < 4; ++td)
                o[td][tq] = __builtin_amdgcn_mfma_f32_16x16x32_f16(vf[td], pb[tq], o[td][tq], 0, 0, 0);
        __builtin_amdgcn_s_setprio(0);
    }
#undef QK_PHASE

    // l partials (Lp is a separate region — safe before the union barrier)
    #pragma unroll
    for (int tq = 0; tq < 4; ++tq) {
        float s = lp[tq];
        s += __shfl_xor(s, 16);
        s += __shfl_xor(s, 32);
        if (quad == 0) Lp[wave*64 + tq*16 + l15] = s;
    }
    __syncthreads();   // all waves done reading Pl+Q before Os overwrites
    {
        unsigned short* ow = &PO[wave*64*OPAD];
        #pragma unroll
        for (int td = 0; td < 4; ++td)
            #pragma unroll
            for (int tq = 0; tq < 4; ++tq) {
                uint2 u; u.x = pkh(o[td][tq][0], o[td][tq][1]); u.y = pkh(o[td][tq][2], o[td][tq][3]);
                *(uint2*)(&ow[(tq*16 + l15)*OPAD + td*16 + quad*4]) = u;
            }
    }
    __syncthreads();
    float* outb = out + (size_t)(b*SEQ + m0) * (NHEADS*DH) + h*DH;
    #pragma unroll
    for (int i = 0; i < 16; ++i) {
        int idx = t + i*256;
        int q = idx >> 6, d = idx & 63;
        float lt = Lp[q] + Lp[64 + q] + Lp[128 + q] + Lp[192 + q];
        float s = 0.f;
        #pragma unroll
        for (int w2 = 0; w2 < 4; ++w2) {
            _Float16 hv = *(const _Float16*)&PO[(w2*64 + q)*OPAD + d];
            s += (float)hv;
        }
        outb[(size_t)q * (NHEADS*DH) + d] = s / lt;
    }
}

extern "C" void kernel_launch(void* const* d_in, const int* in_sizes, int n_in,
                              void* d_out, int out_size, void* d_ws, size_t ws_size,
                              hipStream_t stream) {
    const float* x    = (const float*)d_in[0];
    const float* W    = (const float*)d_in[1];
    const float* bias = (const float*)d_in[2];
    float* out = (float*)d_out;

    unsigned short* xb  = (unsigned short*)d_ws;                 // 16 MB (reused as vtg after GEMM)
    unsigned short* Wt  = xb  + (size_t)MTOT * D_IN;             // 6 MB
    unsigned short* qkv = Wt  + (size_t)NQKV * D_IN;             // 48 MB
    unsigned short* vtg = xb;                                    // alias: xb dead after GEMM

    hipLaunchKernelGGL(k_convert_x,   dim3(MTOT*D_IN/4/256), dim3(256),    0, stream, x, xb);
    hipLaunchKernelGGL(k_convert_wt,  dim3(NQKV/32, D_IN/32), dim3(32, 8), 0, stream, W, Wt);
    hipLaunchKernelGGL(k_gemm_qkv,    dim3(NQKV/128, MTOT/128), dim3(256), 0, stream, xb, Wt, bias, qkv);
    hipLaunchKernelGGL(k_transpose_v, dim3(BATCH*NHEADS, SEQ/64), dim3(256), 0, stream, qkv, vtg);
    hipLaunchKernelGGL(k_attn,        dim3(BATCH*NHEADS, SEQ/64), dim3(256), 0, stream, qkv, vtg, out);
}

// Round 7
// 500.569 us; speedup vs baseline: 1.0735x; 1.0735x over previous
//
#include <hip/hip_runtime.h>
#include <stdint.h>
#include <math.h>

#define D_IN   1024
#define NQKV   3072
#define NHEADS 16
#define DH     64
#define BATCH  4
#define SEQ    2048
#define MTOT   (BATCH*SEQ)   // 8192

typedef __bf16    bf16x8 __attribute__((ext_vector_type(8)));
typedef _Float16  f16x8  __attribute__((ext_vector_type(8)));
typedef float     f32x4  __attribute__((ext_vector_type(4)));
typedef float     f32x16 __attribute__((ext_vector_type(16)));

typedef __attribute__((address_space(3))) unsigned short       lds_us;
typedef __attribute__((address_space(1))) const unsigned short glb_us;

__device__ __forceinline__ unsigned short f2bf(float f) {
    union { float f; uint32_t u; } c; c.f = f;
    uint32_t u = c.u;
    uint32_t r = u + 0x7fffu + ((u >> 16) & 1u);  // RNE
    return (unsigned short)(r >> 16);
}
__device__ __forceinline__ float bf2f(unsigned short b) {
    union { uint32_t u; float f; } c; c.u = ((uint32_t)b) << 16;
    return c.f;
}
__device__ __forceinline__ uint32_t pkh(float a, float b) {
    auto h = __builtin_amdgcn_cvt_pkrtz(a, b);   // __fp16 ext_vector(2): low=a, high=b
    uint32_t u;
    __builtin_memcpy(&u, &h, 4);
    return u;
}

// ---------------- stage 0a: x fp32 -> bf16 ----------------
__global__ void k_convert_x(const float* __restrict__ x, unsigned short* __restrict__ xb) {
    int i = blockIdx.x * 256 + threadIdx.x;
    float4 v = ((const float4*)x)[i];
    ushort4 o;
    o.x = f2bf(v.x); o.y = f2bf(v.y); o.z = f2bf(v.z); o.w = f2bf(v.w);
    ((ushort4*)xb)[i] = o;
}

// ---------------- stage 0b: W fp32 [K][N] -> Wt bf16 [N][K] ----------------
__global__ void k_convert_wt(const float* __restrict__ W, unsigned short* __restrict__ Wt) {
    __shared__ float tile[32][33];
    int tx = threadIdx.x, ty = threadIdx.y;
    int n0 = blockIdx.x * 32, k0 = blockIdx.y * 32;
    #pragma unroll
    for (int i = 0; i < 4; ++i) {
        int k = k0 + ty + i*8;
        tile[ty + i*8][tx] = W[(size_t)k * NQKV + n0 + tx];
    }
    __syncthreads();
    #pragma unroll
    for (int i = 0; i < 4; ++i) {
        int n = n0 + ty + i*8;
        Wt[(size_t)n * D_IN + k0 + tx] = f2bf(tile[tx][ty + i*8]);
    }
}

// ---------------- stage 1: QKV = x @ W + b, m97-style global_load_lds GEMM ----------------
// 128x128 tile, BK=32, unpadded LDS [128][32] (2-way bank alias = free), DMA staging.
// Q columns (col%192 < 64) pre-scaled by 0.125*log2e so k_attn's exp2 needs no mul.
__global__ __launch_bounds__(256) void k_gemm_qkv(
    const unsigned short* __restrict__ A,   // [8192][1024] bf16
    const unsigned short* __restrict__ Bt,  // [3072][1024] bf16
    const float* __restrict__ bias,         // [3072]
    unsigned short* __restrict__ C)         // [8192][3072] bf16
{
    __shared__ __align__(16) unsigned short As[128*32];
    __shared__ __align__(16) unsigned short Bs[128*32];
    const int t = threadIdx.x;
    const int wave = t >> 6, lane = t & 63, quad = lane >> 4, l15 = lane & 15;
    const int wm = wave >> 1, wn = wave & 1;
    const int m0 = blockIdx.y * 128, n0 = blockIdx.x * 128;
    const int crow = lane >> 2;          // row within 16-row chunk
    const int ccol = (lane & 3) << 3;    // short col within row

    f32x4 acc[4][4] = {};
    lds_us* As3 = (lds_us*)As;
    lds_us* Bs3 = (lds_us*)Bs;

    for (int k0 = 0; k0 < D_IN; k0 += 32) {
        // stage A,B tiles: each wave DMAs 2 chunks of 16 rows each (1024 B per instr)
        #pragma unroll
        for (int j = 0; j < 2; ++j) {
            int chunk = wave*2 + j;
            const unsigned short* ga = A  + (size_t)(m0 + chunk*16 + crow)*D_IN + k0 + ccol;
            const unsigned short* gb = Bt + (size_t)(n0 + chunk*16 + crow)*D_IN + k0 + ccol;
            __builtin_amdgcn_global_load_lds((glb_us*)ga, As3 + chunk*512, 16, 0, 0);
            __builtin_amdgcn_global_load_lds((glb_us*)gb, Bs3 + chunk*512, 16, 0, 0);
        }
        __syncthreads();   // drains vmcnt -> staging visible
        bf16x8 a[4], b[4];
        #pragma unroll
        for (int tm = 0; tm < 4; ++tm)
            a[tm] = *(const bf16x8*)(&As[(wm*64 + tm*16 + l15)*32 + quad*8]);
        #pragma unroll
        for (int tn = 0; tn < 4; ++tn)
            b[tn] = *(const bf16x8*)(&Bs[(wn*64 + tn*16 + l15)*32 + quad*8]);
        #pragma unroll
        for (int tm = 0; tm < 4; ++tm)
            #pragma unroll
            for (int tn = 0; tn < 4; ++tn)
                acc[tm][tn] = __builtin_amdgcn_mfma_f32_16x16x32_bf16(a[tm], b[tn], acc[tm][tn], 0, 0, 0);
        __syncthreads();   // protect LDS before next iteration's DMA overwrite
    }
    const float qs = 0.125f * 1.44269504089f;
    #pragma unroll
    for (int tn = 0; tn < 4; ++tn) {
        int col = n0 + wn*64 + tn*16 + l15;
        float bv = bias[col];
        float s = ((col % 192) < 64) ? qs : 1.0f;   // pre-scale Q columns
        #pragma unroll
        for (int tm = 0; tm < 4; ++tm) {
            #pragma unroll
            for (int r = 0; r < 4; ++r) {
                int row = m0 + wm*64 + tm*16 + quad*4 + r;
                C[(size_t)row*NQKV + col] = f2bf((acc[tm][tn][r] + bv) * s);
            }
        }
    }
}

// ---------------- stage 1b: V (bf16, strided in qkv) -> Vt f16 [bh][d][s] ----------------
// grid (bh, s-tile): all of one bh's V^T written on ONE XCD's L2 (matches k_attn's mapping).
#define TP 66
__global__ __launch_bounds__(256) void k_transpose_v(
    const unsigned short* __restrict__ qkv,
    unsigned short* __restrict__ vtg)       // f16 bits
{
    __shared__ unsigned short T[64*TP];     // [s][d] as f16
    const int t = threadIdx.x;
    const int bh = blockIdx.x, b = bh >> 4, h = bh & 15;
    const int s0 = blockIdx.y * 64;
    const unsigned short* src = qkv + (size_t)(b*SEQ + s0)*NQKV + h*(3*DH) + 2*DH;
    #pragma unroll
    for (int i = 0; i < 2; ++i) {
        int idx = t + i*256;
        int s = idx >> 3, c = (idx & 7) << 3;
        uint4 v = *(const uint4*)(src + (size_t)s*NQKV + c);   // 16 B = 8 bf16
        unsigned short* dst = &T[s*TP + c];
        const unsigned short* pv = (const unsigned short*)&v;
        #pragma unroll
        for (int j = 0; j < 8; ++j) {
            _Float16 hv = (_Float16)bf2f(pv[j]);
            dst[j] = *(unsigned short*)&hv;
        }
    }
    __syncthreads();
    unsigned short* out = vtg + (size_t)bh * DH * SEQ + s0;
    #pragma unroll
    for (int i = 0; i < 16; ++i) {
        int idx = t + i*256;
        int d = idx >> 6, s = idx & 63;
        out[(size_t)d * SEQ + s] = T[s*TP + d];
    }
}

// ---------------- stage 2: flash attention, ZERO-LDS, 32x32 MFMA, layout-agnostic PV ----------------
// R6 (resubmitted after infra failure): fix R5's correctness failure. R5 depended on
// two UNVERIFIED mappings: the 32x32x16 A/B k_inst layout and v_permlane32_swap
// direction. Both are now removed:
//  * QK is layout-agnostic by construction (A=K and B=Q use identical elem->global-k
//    placement; contraction correct under ANY bijective hardware mapping).
//  * PV hand-off: the QK C-layout (HW-verified m74/m101: lane(l31,hi) reg r holds
//    key (r&3)+8*(r>>2)+4*hi, q=l31) means after pairwise cvt_pkrtz the lane's words
//    w0..w3 cover keys 4hi+{0,1}, 4hi+{2,3}, 8+4hi+{0,1}, 8+4hi+{2,3} per 16-key
//    group. USE THAT ORDER AS THE B-FRAGMENT (no cross-lane exchange), and load the
//    V A-fragment with the SAME elem->key placement: elem j <- V^T[d][key0 + 16*kh
//    + 4*hi + (j&3) + 8*(j>>2)] (two 8B loads per fragment). A and B agree on every
//    (hi,j) position -> correct under any hardware k_inst mapping. Only remaining
//    layout dependency is the 32x32 C/D layout (HW-verified, dtype-independent).
// Structure (unchanged from R5): wave owns 32 q-rows, iterates all 2048 keys in
// 32-key chunks; no __shared__, no barriers; K/V single-buffered in regs, reloaded
// right after last use; O acc = 32 AGPRs; l-sum per-lane + one shfl_xor(32).
__global__ __launch_bounds__(256) void k_attn(
    const unsigned short* __restrict__ qkv, // bf16 (Q pre-scaled by 0.125*log2e)
    const unsigned short* __restrict__ vtg, // f16 V^T [bh][d][s]
    float* __restrict__ out)
{
    const int t = threadIdx.x;
    const int wave = t >> 6, lane = t & 63;
    const int l31 = lane & 31, hi = lane >> 5;
    const int bh = blockIdx.x, b = bh >> 4, h = bh & 15;
    const int q0 = blockIdx.y * 128 + wave * 32;

    const unsigned short* qrow  = qkv + (size_t)(b*SEQ + q0 + l31)*NQKV + h*(3*DH);
    const unsigned short* kbase = qkv + (size_t)(b*SEQ)*NQKV + h*(3*DH) + DH;
    const unsigned short* vbase = vtg + (size_t)bh * DH * SEQ;

    // Q B-frags: n = q = q0+l31, elem j of frag st at global dk = st*16 + hi*8 + j.
    bf16x8 qf[4];
    #pragma unroll
    for (int st = 0; st < 4; ++st)
        qf[st] = *(const bf16x8*)(qrow + st*16 + hi*8);

    // running chunk pointers (chunk = 32 keys)
    const unsigned short* kn = kbase + (size_t)l31*NQKV + hi*8;   // += 32*NQKV per chunk
    const unsigned short* vn = vbase + (size_t)l31*SEQ + 4*hi;    // += 32 per chunk

    // K A-frags: m = key = key0+l31, elem j of frag st at dk = st*16 + hi*8 + j
    // (same placement as qf -> QK correct under any k_inst mapping)
    bf16x8 kf[4];
    #pragma unroll
    for (int st = 0; st < 4; ++st)
        kf[st] = *(const bf16x8*)(kn + st*16);

    // V A-frags: m = d = dt*32 + l31; elem j at key = key0 + 16*kh + 4*hi + (j&3) + 8*(j>>2)
    // -> two 8B loads: elems 0-3 at s-offset 16*kh + 4*hi, elems 4-7 at +8.
    f16x8 vf[2][2];
    #pragma unroll
    for (int dt = 0; dt < 2; ++dt)
        #pragma unroll
        for (int kh = 0; kh < 2; ++kh) {
            uint2 lo = *(const uint2*)(vn + (size_t)dt*32*SEQ + kh*16);
            uint2 hi4 = *(const uint2*)(vn + (size_t)dt*32*SEQ + kh*16 + 8);
            union { uint32_t u[4]; f16x8 v; } cc;
            cc.u[0] = lo.x; cc.u[1] = lo.y; cc.u[2] = hi4.x; cc.u[3] = hi4.y;
            vf[dt][kh] = cc.v;
        }

    f32x16 o0 = {}, o1 = {};   // O^T tiles: d = dt*32 + (reg&3)+8*(reg>>2)+4*hi, q = l31
    float lp = 0.f;

    for (int it = 0; it < 64; ++it) {
        // QK: S^T[key][q], key = (reg&3)+8*(reg>>2)+4*hi (+it*32), q = q0+l31
        f32x16 s = {};
        __builtin_amdgcn_s_setprio(1);
        #pragma unroll
        for (int st = 0; st < 4; ++st)
            s = __builtin_amdgcn_mfma_f32_32x32x16_bf16(kf[st], qf[st], s, 0, 0, 0);
        __builtin_amdgcn_s_setprio(0);
        // kf consumed -> reload next chunk (exp+PV hides ~L2 latency)
        if (it < 63) {
            kn += (size_t)32*NQKV;
            #pragma unroll
            for (int st = 0; st < 4; ++st)
                kf[st] = *(const bf16x8*)(kn + st*16);
        }
        // exp2 (scale pre-folded into Q), l-partials, pack key-pairs to f16.
        // w0..w3 = keys {4hi+0,4hi+1},{4hi+2,4hi+3},{8+4hi+0,8+4hi+1},{8+4hi+2,8+4hi+3}
        // w4..w7 = same +16. These ARE the PV B-fragments in this elem order.
        uint32_t w0, w1, w2, w3, w4, w5, w6, w7;
        {
            float p0, p1, p2, p3;
            p0 = exp2f(s[0]);  p1 = exp2f(s[1]);  p2 = exp2f(s[2]);  p3 = exp2f(s[3]);
            lp += (p0+p1)+(p2+p3); w0 = pkh(p0,p1); w1 = pkh(p2,p3);
            p0 = exp2f(s[4]);  p1 = exp2f(s[5]);  p2 = exp2f(s[6]);  p3 = exp2f(s[7]);
            lp += (p0+p1)+(p2+p3); w2 = pkh(p0,p1); w3 = pkh(p2,p3);
            p0 = exp2f(s[8]);  p1 = exp2f(s[9]);  p2 = exp2f(s[10]); p3 = exp2f(s[11]);
            lp += (p0+p1)+(p2+p3); w4 = pkh(p0,p1); w5 = pkh(p2,p3);
            p0 = exp2f(s[12]); p1 = exp2f(s[13]); p2 = exp2f(s[14]); p3 = exp2f(s[15]);
            lp += (p0+p1)+(p2+p3); w6 = pkh(p0,p1); w7 = pkh(p2,p3);
        }
        f16x8 pf0, pf1;
        {
            union { uint32_t u[4]; f16x8 v; } cc;
            cc.u[0] = w0; cc.u[1] = w1; cc.u[2] = w2; cc.u[3] = w3; pf0 = cc.v;
            cc.u[0] = w4; cc.u[1] = w5; cc.u[2] = w6; cc.u[3] = w7; pf1 = cc.v;
        }
        // PV: O^T += V^T · P^T  (A/B elem->key placements identical by construction)
        __builtin_amdgcn_s_setprio(1);
        o0 = __builtin_amdgcn_mfma_f32_32x32x16_f16(vf[0][0], pf0, o0, 0, 0, 0);
        o1 = __builtin_amdgcn_mfma_f32_32x32x16_f16(vf[1][0], pf0, o1, 0, 0, 0);
        o0 = __builtin_amdgcn_mfma_f32_32x32x16_f16(vf[0][1], pf1, o0, 0, 0, 0);
        o1 = __builtin_amdgcn_mfma_f32_32x32x16_f16(vf[1][1], pf1, o1, 0, 0, 0);
        __builtin_amdgcn_s_setprio(0);
        // vf consumed -> reload next chunk (next QK hides the latency)
        if (it < 63) {
            vn += 32;
            #pragma unroll
            for (int dt = 0; dt < 2; ++dt)
                #pragma unroll
                for (int kh = 0; kh < 2; ++kh) {
                    uint2 lo = *(const uint2*)(vn + (size_t)dt*32*SEQ + kh*16);
                    uint2 hi4 = *(const uint2*)(vn + (size_t)dt*32*SEQ + kh*16 + 8);
                    union { uint32_t u[4]; f16x8 v; } cc;
                    cc.u[0] = lo.x; cc.u[1] = lo.y; cc.u[2] = hi4.x; cc.u[3] = hi4.y;
                    vf[dt][kh] = cc.v;
                }
        }
    }

    // l: the two half-lanes of each q hold disjoint key sets
    float lt = lp + __shfl_xor(lp, 32);
    float rl = 1.0f / lt;

    // out[b, q, h*64 + d]; o0[4g+c] is at d = 8g + 4hi + c (c=0..3), o1 at d+32
    float* outb = out + (size_t)(b*SEQ + q0 + l31)*(NHEADS*DH) + h*DH + 4*hi;
    #pragma unroll
    for (int g = 0; g < 4; ++g) {
        float4 v0 = make_float4(o0[4*g]*rl, o0[4*g+1]*rl, o0[4*g+2]*rl, o0[4*g+3]*rl);
        float4 v1 = make_float4(o1[4*g]*rl, o1[4*g+1]*rl, o1[4*g+2]*rl, o1[4*g+3]*rl);
        *(float4*)(outb + 8*g)      = v0;
        *(float4*)(outb + 32 + 8*g) = v1;
    }
}

extern "C" void kernel_launch(void* const* d_in, const int* in_sizes, int n_in,
                              void* d_out, int out_size, void* d_ws, size_t ws_size,
                              hipStream_t stream) {
    const float* x    = (const float*)d_in[0];
    const float* W    = (const float*)d_in[1];
    const float* bias = (const float*)d_in[2];
    float* out = (float*)d_out;

    unsigned short* xb  = (unsigned short*)d_ws;                 // 16 MB (reused as vtg after GEMM)
    unsigned short* Wt  = xb  + (size_t)MTOT * D_IN;             // 6 MB
    unsigned short* qkv = Wt  + (size_t)NQKV * D_IN;             // 48 MB
    unsigned short* vtg = xb;                                    // alias: xb dead after GEMM

    hipLaunchKernelGGL(k_convert_x,   dim3(MTOT*D_IN/4/256), dim3(256),    0, stream, x, xb);
    hipLaunchKernelGGL(k_convert_wt,  dim3(NQKV/32, D_IN/32), dim3(32, 8), 0, stream, W, Wt);
    hipLaunchKernelGGL(k_gemm_qkv,    dim3(NQKV/128, MTOT/128), dim3(256), 0, stream, xb, Wt, bias, qkv);
    hipLaunchKernelGGL(k_transpose_v, dim3(BATCH*NHEADS, SEQ/64), dim3(256), 0, stream, qkv, vtg);
    hipLaunchKernelGGL(k_attn,        dim3(BATCH*NHEADS, SEQ/128), dim3(256), 0, stream, qkv, vtg, out);
}

// Round 8
// 279.549 us; speedup vs baseline: 1.9223x; 1.7906x over previous
//
#include <hip/hip_runtime.h>
#include <stdint.h>
#include <math.h>

#define D_IN   1024
#define NQKV   3072
#define NHEADS 16
#define DH     64
#define BATCH  4
#define SEQ    2048
#define MTOT   (BATCH*SEQ)   // 8192

typedef __bf16    bf16x8 __attribute__((ext_vector_type(8)));
typedef _Float16  f16x8  __attribute__((ext_vector_type(8)));
typedef float     f32x4  __attribute__((ext_vector_type(4)));
typedef float     f32x16 __attribute__((ext_vector_type(16)));

typedef __attribute__((address_space(3))) unsigned short       lds_us;
typedef __attribute__((address_space(1))) const unsigned short glb_us;

__device__ __forceinline__ unsigned short f2bf(float f) {
    union { float f; uint32_t u; } c; c.f = f;
    uint32_t u = c.u;
    uint32_t r = u + 0x7fffu + ((u >> 16) & 1u);  // RNE
    return (unsigned short)(r >> 16);
}
__device__ __forceinline__ uint32_t pkh(float a, float b) {
    auto h = __builtin_amdgcn_cvt_pkrtz(a, b);   // __fp16 ext_vector(2): low=a, high=b
    uint32_t u;
    __builtin_memcpy(&u, &h, 4);
    return u;
}

// ---------------- stage 0a: x fp32 -> bf16 ----------------
__global__ void k_convert_x(const float* __restrict__ x, unsigned short* __restrict__ xb) {
    int i = blockIdx.x * 256 + threadIdx.x;
    float4 v = ((const float4*)x)[i];
    ushort4 o;
    o.x = f2bf(v.x); o.y = f2bf(v.y); o.z = f2bf(v.z); o.w = f2bf(v.w);
    ((ushort4*)xb)[i] = o;
}

// ---------------- stage 0b: W fp32 [K][N] -> Wt bf16 [N][K] ----------------
__global__ void k_convert_wt(const float* __restrict__ W, unsigned short* __restrict__ Wt) {
    __shared__ float tile[32][33];
    int tx = threadIdx.x, ty = threadIdx.y;
    int n0 = blockIdx.x * 32, k0 = blockIdx.y * 32;
    #pragma unroll
    for (int i = 0; i < 4; ++i) {
        int k = k0 + ty + i*8;
        tile[ty + i*8][tx] = W[(size_t)k * NQKV + n0 + tx];
    }
    __syncthreads();
    #pragma unroll
    for (int i = 0; i < 4; ++i) {
        int n = n0 + ty + i*8;
        Wt[(size_t)n * D_IN + k0 + tx] = f2bf(tile[tx][ty + i*8]);
    }
}

// ---------------- stage 1: QKV GEMM with FRAGMENT-SCATTER epilogue ----------------
// R8: the epilogue no longer writes a row-major qkv. It writes three buffers in the
// exact per-lane fragment order k_attn consumes, so every k_attn load is a fully
// coalesced 1KB wave-read (R7 post-mortem: per-lane row-scatter loads expanded to
// ~32 L2 transactions each; the L2 request path was the bottleneck, MfmaUtil 7.7%).
//   Qbuf [row][h][dk]                       bf16, pre-scaled 0.125*log2e
//   Kfrag[bh][chunk][st][lane(hi,l31)][j]   bf16: elem j = K[key=chunk*32+l31][dk=st*16+hi*8+j]
//   Vfrag[bh][chunk][dt][kh][lane(hi,l31)][j] f16: elem j = V[key=chunk*32+16*kh+4*hi+(j&3)+8*(j>>2)][d=dt*32+l31]
// These are the SAME elem->key placements the (passing) R6 kernel used -> correctness
// transfers. Uniformity: each tn's 16-col run lies in one 64-aligned run; 192-pattern
// boundaries are multiples of 64 -> (kind, h) are wave-uniform per tn.
__global__ __launch_bounds__(256) void k_gemm_qkv(
    const unsigned short* __restrict__ A,   // [8192][1024] bf16
    const unsigned short* __restrict__ Bt,  // [3072][1024] bf16
    const float* __restrict__ bias,         // [3072]
    unsigned short* __restrict__ Qb,        // [8192][1024] bf16
    unsigned short* __restrict__ Kf,        // fragment layout, 8M shorts
    unsigned short* __restrict__ Vf)        // fragment layout, 8M shorts (f16)
{
    __shared__ __align__(16) unsigned short As[128*32];
    __shared__ __align__(16) unsigned short Bs[128*32];
    const int t = threadIdx.x;
    const int wave = t >> 6, lane = t & 63, quad = lane >> 4, l15 = lane & 15;
    const int wm = wave >> 1, wn = wave & 1;
    const int m0 = blockIdx.y * 128, n0 = blockIdx.x * 128;
    const int crow = lane >> 2;          // row within 16-row chunk
    const int ccol = (lane & 3) << 3;    // short col within row

    f32x4 acc[4][4] = {};
    lds_us* As3 = (lds_us*)As;
    lds_us* Bs3 = (lds_us*)Bs;

    for (int k0 = 0; k0 < D_IN; k0 += 32) {
        #pragma unroll
        for (int j = 0; j < 2; ++j) {
            int chunk = wave*2 + j;
            const unsigned short* ga = A  + (size_t)(m0 + chunk*16 + crow)*D_IN + k0 + ccol;
            const unsigned short* gb = Bt + (size_t)(n0 + chunk*16 + crow)*D_IN + k0 + ccol;
            __builtin_amdgcn_global_load_lds((glb_us*)ga, As3 + chunk*512, 16, 0, 0);
            __builtin_amdgcn_global_load_lds((glb_us*)gb, Bs3 + chunk*512, 16, 0, 0);
        }
        __syncthreads();
        bf16x8 a[4], b[4];
        #pragma unroll
        for (int tm = 0; tm < 4; ++tm)
            a[tm] = *(const bf16x8*)(&As[(wm*64 + tm*16 + l15)*32 + quad*8]);
        #pragma unroll
        for (int tn = 0; tn < 4; ++tn)
            b[tn] = *(const bf16x8*)(&Bs[(wn*64 + tn*16 + l15)*32 + quad*8]);
        #pragma unroll
        for (int tm = 0; tm < 4; ++tm)
            #pragma unroll
            for (int tn = 0; tn < 4; ++tn)
                acc[tm][tn] = __builtin_amdgcn_mfma_f32_16x16x32_bf16(a[tm], b[tn], acc[tm][tn], 0, 0, 0);
        __syncthreads();
    }
    const float qs = 0.125f * 1.44269504089f;
    #pragma unroll
    for (int tn = 0; tn < 4; ++tn) {
        const int col0 = n0 + wn*64 + tn*16;     // lane-uniform
        const int h   = col0 / 192;
        const int r0  = col0 - h*192;            // 0..191, run of 16 stays in one kind
        const float bv = bias[col0 + l15];
        if (r0 < 64) {
            // ---- Q: Qbuf[row][h*64 + dk], scaled ----
            const int dk = r0 + l15;
            #pragma unroll
            for (int tm = 0; tm < 4; ++tm)
                #pragma unroll
                for (int r = 0; r < 4; ++r) {
                    int row = m0 + wm*64 + tm*16 + quad*4 + r;
                    Qb[(size_t)row*1024 + h*64 + dk] = f2bf((acc[tm][tn][r] + bv) * qs);
                }
        } else if (r0 < 128) {
            // ---- K fragment scatter ----
            const int dk = r0 - 64 + l15;
            const int st = dk >> 4, hi2 = (dk >> 3) & 1, j = dk & 7;
            #pragma unroll
            for (int tm = 0; tm < 4; ++tm)
                #pragma unroll
                for (int r = 0; r < 4; ++r) {
                    int row = m0 + wm*64 + tm*16 + quad*4 + r;
                    int bh = ((row >> 11) << 4) + h;
                    int chunk = (row >> 5) & 63, l31r = row & 31;
                    Kf[((size_t)(bh*64 + chunk)*4 + st)*512 + (hi2*32 + l31r)*8 + j] =
                        f2bf(acc[tm][tn][r] + bv);
                }
        } else {
            // ---- V fragment scatter (f16) ----
            const int d = r0 - 128 + l15;
            const int dt = d >> 5, l31d = d & 31;
            #pragma unroll
            for (int tm = 0; tm < 4; ++tm)
                #pragma unroll
                for (int r = 0; r < 4; ++r) {
                    int row = m0 + wm*64 + tm*16 + quad*4 + r;
                    int bh = ((row >> 11) << 4) + h;
                    int chunk = (row >> 5) & 63;
                    int kc = row & 31, kh = kc >> 4, rem = kc & 15;
                    int hi2 = (rem >> 2) & 1;
                    int j = (rem & 3) | (((rem >> 3) & 1) << 2);
                    _Float16 hv = (_Float16)(acc[tm][tn][r] + bv);
                    Vf[(((size_t)(bh*64 + chunk)*2 + dt)*2 + kh)*512 + (hi2*32 + l31d)*8 + j] =
                        *(unsigned short*)&hv;
                }
        }
    }
}

// ---------------- stage 2: flash attention, ZERO-LDS, 32x32 MFMA, coalesced frags ----------------
// R8: same verified structure/math as R6 (passed, absmax 0.0039), but every in-loop
// load is now a contiguous 1KB wave-read from Kfrag/Vfrag (lane-indexed). Per iter:
// 4 kf + 4 vf loads (vf was 8 sub-loads, now 4). No __shared__, no barriers.
__global__ __launch_bounds__(256) void k_attn(
    const unsigned short* __restrict__ Qb,  // [8192][1024] bf16 (pre-scaled)
    const unsigned short* __restrict__ Kf,  // fragment layout bf16
    const unsigned short* __restrict__ Vf,  // fragment layout f16
    float* __restrict__ out)
{
    const int t = threadIdx.x;
    const int wave = t >> 6, lane = t & 63;
    const int l31 = lane & 31, hi = lane >> 5;
    const int bh = blockIdx.x, b = bh >> 4, h = bh & 15;
    const int q0 = blockIdx.y * 128 + wave * 32;

    const unsigned short* qrow = Qb + (size_t)(b*SEQ + q0 + l31)*1024 + h*64;
    const unsigned short* kfb  = Kf + (size_t)bh * 64*4*512 + lane*8;       // + (chunk*4+st)*512
    const unsigned short* vfb  = Vf + (size_t)bh * 64*2*2*512 + lane*8;     // + ((chunk*2+dt)*2+kh)*512

    // Q B-frags: n = q = q0+l31, elem j of frag st at global dk = st*16 + hi*8 + j.
    bf16x8 qf[4];
    #pragma unroll
    for (int st = 0; st < 4; ++st)
        qf[st] = *(const bf16x8*)(qrow + st*16 + hi*8);

    // K A-frags (same elem->dk placement as qf -> QK correct under any k_inst mapping)
    bf16x8 kf[4];
    #pragma unroll
    for (int st = 0; st < 4; ++st)
        kf[st] = *(const bf16x8*)(kfb + st*512);
    // V A-frags (elem->key placement matches the packed P word order)
    f16x8 vf[2][2];
    #pragma unroll
    for (int dt = 0; dt < 2; ++dt)
        #pragma unroll
        for (int kh = 0; kh < 2; ++kh)
            vf[dt][kh] = *(const f16x8*)(vfb + (dt*2 + kh)*512);

    f32x16 o0 = {}, o1 = {};   // O^T tiles: d = dt*32 + (reg&3)+8*(reg>>2)+4*hi, q = l31
    float lp = 0.f;

    for (int it = 0; it < 64; ++it) {
        // QK: S^T[key][q], key = (reg&3)+8*(reg>>2)+4*hi (+it*32), q = q0+l31
        f32x16 s = {};
        __builtin_amdgcn_s_setprio(1);
        #pragma unroll
        for (int st = 0; st < 4; ++st)
            s = __builtin_amdgcn_mfma_f32_32x32x16_bf16(kf[st], qf[st], s, 0, 0, 0);
        __builtin_amdgcn_s_setprio(0);
        // kf consumed -> reload next chunk (exp+PV hides the latency)
        if (it < 63) {
            const unsigned short* kn = kfb + (size_t)(it+1)*4*512;
            #pragma unroll
            for (int st = 0; st < 4; ++st)
                kf[st] = *(const bf16x8*)(kn + st*512);
        }
        // exp2 (scale pre-folded into Q), l-partials, pack key-pairs to f16.
        // w0..w3 cover keys {4hi+0,1},{4hi+2,3},{8+4hi+0,1},{8+4hi+2,3}; w4..w7 same +16.
        uint32_t w0, w1, w2, w3, w4, w5, w6, w7;
        {
            float p0, p1, p2, p3;
            p0 = exp2f(s[0]);  p1 = exp2f(s[1]);  p2 = exp2f(s[2]);  p3 = exp2f(s[3]);
            lp += (p0+p1)+(p2+p3); w0 = pkh(p0,p1); w1 = pkh(p2,p3);
            p0 = exp2f(s[4]);  p1 = exp2f(s[5]);  p2 = exp2f(s[6]);  p3 = exp2f(s[7]);
            lp += (p0+p1)+(p2+p3); w2 = pkh(p0,p1); w3 = pkh(p2,p3);
            p0 = exp2f(s[8]);  p1 = exp2f(s[9]);  p2 = exp2f(s[10]); p3 = exp2f(s[11]);
            lp += (p0+p1)+(p2+p3); w4 = pkh(p0,p1); w5 = pkh(p2,p3);
            p0 = exp2f(s[12]); p1 = exp2f(s[13]); p2 = exp2f(s[14]); p3 = exp2f(s[15]);
            lp += (p0+p1)+(p2+p3); w6 = pkh(p0,p1); w7 = pkh(p2,p3);
        }
        f16x8 pf0, pf1;
        {
            union { uint32_t u[4]; f16x8 v; } cc;
            cc.u[0] = w0; cc.u[1] = w1; cc.u[2] = w2; cc.u[3] = w3; pf0 = cc.v;
            cc.u[0] = w4; cc.u[1] = w5; cc.u[2] = w6; cc.u[3] = w7; pf1 = cc.v;
        }
        // PV: O^T += V^T · P^T  (A/B elem->key placements identical by construction)
        __builtin_amdgcn_s_setprio(1);
        o0 = __builtin_amdgcn_mfma_f32_32x32x16_f16(vf[0][0], pf0, o0, 0, 0, 0);
        o1 = __builtin_amdgcn_mfma_f32_32x32x16_f16(vf[1][0], pf0, o1, 0, 0, 0);
        o0 = __builtin_amdgcn_mfma_f32_32x32x16_f16(vf[0][1], pf1, o0, 0, 0, 0);
        o1 = __builtin_amdgcn_mfma_f32_32x32x16_f16(vf[1][1], pf1, o1, 0, 0, 0);
        __builtin_amdgcn_s_setprio(0);
        // vf consumed -> reload next chunk (next QK hides the latency)
        if (it < 63) {
            const unsigned short* vn = vfb + (size_t)(it+1)*4*512;
            #pragma unroll
            for (int dt = 0; dt < 2; ++dt)
                #pragma unroll
                for (int kh = 0; kh < 2; ++kh)
                    vf[dt][kh] = *(const f16x8*)(vn + (dt*2 + kh)*512);
        }
    }

    // l: the two half-lanes of each q hold disjoint key sets
    float lt = lp + __shfl_xor(lp, 32);
    float rl = 1.0f / lt;

    // out[b, q, h*64 + d]; o0[4g+c] is at d = 8g + 4hi + c (c=0..3), o1 at d+32
    float* outb = out + (size_t)(b*SEQ + q0 + l31)*(NHEADS*DH) + h*DH + 4*hi;
    #pragma unroll
    for (int g = 0; g < 4; ++g) {
        float4 v0 = make_float4(o0[4*g]*rl, o0[4*g+1]*rl, o0[4*g+2]*rl, o0[4*g+3]*rl);
        float4 v1 = make_float4(o1[4*g]*rl, o1[4*g+1]*rl, o1[4*g+2]*rl, o1[4*g+3]*rl);
        *(float4*)(outb + 8*g)      = v0;
        *(float4*)(outb + 32 + 8*g) = v1;
    }
}

extern "C" void kernel_launch(void* const* d_in, const int* in_sizes, int n_in,
                              void* d_out, int out_size, void* d_ws, size_t ws_size,
                              hipStream_t stream) {
    const float* x    = (const float*)d_in[0];
    const float* W    = (const float*)d_in[1];
    const float* bias = (const float*)d_in[2];
    float* out = (float*)d_out;

    // workspace: 73.4 MB total, identical footprint to the old xb+Wt+qkv layout
    unsigned short* xb = (unsigned short*)d_ws;                  // 8388608 shorts (16 MB)
    unsigned short* Wt = xb + (size_t)MTOT * D_IN;               // 3145728 shorts (6 MB)
    unsigned short* Qb = Wt + (size_t)NQKV * D_IN;               // 8388608 shorts (16 MB)
    unsigned short* Kf = Qb + (size_t)MTOT * D_IN;               // 8388608 shorts (16 MB)
    unsigned short* Vf = Kf + (size_t)MTOT * D_IN;               // 8388608 shorts (16 MB)

    hipLaunchKernelGGL(k_convert_x,  dim3(MTOT*D_IN/4/256), dim3(256),    0, stream, x, xb);
    hipLaunchKernelGGL(k_convert_wt, dim3(NQKV/32, D_IN/32), dim3(32, 8), 0, stream, W, Wt);
    hipLaunchKernelGGL(k_gemm_qkv,   dim3(NQKV/128, MTOT/128), dim3(256), 0, stream, xb, Wt, bias, Qb, Kf, Vf);
    hipLaunchKernelGGL(k_attn,       dim3(BATCH*NHEADS, SEQ/128), dim3(256), 0, stream, Qb, Kf, Vf, out);
}